// Round 1
// baseline (205.686 us; speedup 1.0000x reference)
//
#include <hip/hip_runtime.h>

constexpr int Bn  = 1024;
constexpr int Tn  = 8192;
constexpr int Wn  = 2048;   // NUM_WORDS
constexpr int TPB = 512;
constexpr int NCHUNK = 4;
constexpr int CHUNK  = Tn / NCHUNK;   // 2048 = TPB*4

// Per-position rule evaluation (matches the vectorized reference exactly):
//   INIT_TOKENS  = {94,122,100,92,43,27} -> INIT_DURS {2,3,2,2,5,5}
//   RATIO_TOKENS = {44,28,29,27,121,43}
__device__ __forceinline__ void rule_eval(float dp, float dpn, int tok, bool valid_next,
                                          float& g1, float& g2, float& sa) {
  float expected;
  bool in_init = true;
  switch (tok) {
    case 94:  expected = 2.f; break;
    case 122: expected = 3.f; break;
    case 100: expected = 2.f; break;
    case 92:  expected = 2.f; break;
    case 43:  expected = 5.f; break;
    case 27:  expected = 5.f; break;
    default:  expected = 0.f; in_init = false; break;
  }
  float t1 = dp - expected;
  bool fire1 = in_init && (t1 > 0.f);
  g1 = fire1 ? t1 : 0.f;
  bool in_ratio = (tok == 44) | (tok == 28) | (tok == 29) |
                  (tok == 27) | (tok == 121) | (tok == 43);
  bool fire2 = in_ratio && valid_next && (3.f * dp > dpn);
  g2 = fire2 ? (dp - dpn * (1.f / 3.f)) : 0.f;
  sa = fire2 ? g2 : (fire1 ? g1 : 0.f);
}

__device__ __forceinline__ float wave_reduce(float v) {
  #pragma unroll
  for (int o = 32; o > 0; o >>= 1) v += __shfl_down(v, o, 64);
  return v;
}

// 2 blocks/CU at <=128 VGPR (512 threads = 8 waves; 4 waves/EU -> 16 waves/CU)
__global__ __launch_bounds__(TPB, 4) void loss_kernel(
    const float* __restrict__ dur_pred, const float* __restrict__ dur_gt,
    const int* __restrict__ ph2word, const int* __restrict__ txt,
    double* __restrict__ acc)
{
  __shared__ float wp[Wn];
  __shared__ float wg[Wn];
  __shared__ float sacc[5];   // pdur_s, rules_s, sp, sg, wd_s

  const int row = blockIdx.x;
  const size_t roff = (size_t)row * Tn;
  const float* __restrict__ dpr = dur_pred + roff;
  const float* __restrict__ dgr = dur_gt + roff;
  const int*   __restrict__ pwr = ph2word + roff;
  const int*   __restrict__ tkr = txt + roff;

  // vectorized LDS zero: Wn/4 == TPB -> exactly one float4 store per thread per array
  {
    const float4 z = {0.f, 0.f, 0.f, 0.f};
    int i = threadIdx.x;
    *reinterpret_cast<float4*>(&wp[i * 4]) = z;
    *reinterpret_cast<float4*>(&wg[i * 4]) = z;
  }
  if (threadIdx.x < 5) sacc[threadIdx.x] = 0.f;
  __syncthreads();

  float pdur_s = 0.f, rules_s = 0.f, sp = 0.f, sg = 0.f;
  const int lane = threadIdx.x & 63;

  #pragma unroll
  for (int c = 0; c < NCHUNK; ++c) {
    const int base = c * CHUNK + threadIdx.x * 4;

    float4 dp4 = *reinterpret_cast<const float4*>(dpr + base);
    float4 dg4 = *reinterpret_cast<const float4*>(dgr + base);
    int4   pw4 = *reinterpret_cast<const int4*>(pwr + base);
    int4   tk4 = *reinterpret_cast<const int4*>(tkr + base);

    // rule evals for own positions j=0..2 (next-neighbor dp is in-register)
    float g1v[4], g2v[4], sav[4];
    rule_eval(dp4.x, dp4.y, tk4.x, true, g1v[0], g2v[0], sav[0]);
    rule_eval(dp4.y, dp4.z, tk4.y, true, g1v[1], g2v[1], sav[1]);
    rule_eval(dp4.z, dp4.w, tk4.z, true, g1v[2], g2v[2], sav[2]);
    float gg0 = g1v[0] + g2v[0];

    // neighbor values for position base+3: dp[base+4] and (g1+g2)[base+4].
    // Thread t+1 holds both (its j=0 eval is purely local) -> shuffle.
    float dpn3 = __shfl_down(dp4.x, 1, 64);
    float ggn  = __shfl_down(gg0,   1, 64);
    if (lane == 63) {  // cross-wave / chunk boundary: fall back to (L1-hot) loads
      if (base + 4 < Tn) {
        float a  = dpr[base + 4];
        float b  = (base + 5 < Tn) ? dpr[base + 5] : 0.f;
        int   tn = tkr[base + 4];
        float ng1, ng2, nsa;
        rule_eval(a, b, tn, base + 4 < Tn - 1, ng1, ng2, nsa);
        dpn3 = a; ggn = ng1 + ng2;
      } else {           // base+3 == Tn-1: no next position
        dpn3 = 0.f; ggn = 0.f;
      }
    }
    rule_eval(dp4.w, dpn3, tk4.w, base + 3 < Tn - 1, g1v[3], g2v[3], sav[3]);

    float dpx[4] = {dp4.x, dp4.y, dp4.z, dp4.w};
    float dgl[4] = {dg4.x, dg4.y, dg4.z, dg4.w};
    float addv[4] = {g1v[1] + g2v[1], g1v[2] + g2v[2], g1v[3] + g2v[3], ggn};

    #pragma unroll
    for (int j = 0; j < 4; ++j) {
      float dp = dpx[j];
      float dr = dp - sav[j] + addv[j];        // dur_rules[i]
      float lp = __logf(dp + 1.f);
      float dlr = lp - __logf(dr + 1.f);
      rules_s += dlr * dlr;
      float dlg = lp - __logf(dgl[j] + 1.f);
      pdur_s += dlg * dlg;
      sp += fmaxf(dp, 0.f);
      sg += dgl[j];
    }

    // word segment sums: ph2word sorted per row -> run-compress, LDS atomics
    int pwl[4] = {pw4.x, pw4.y, pw4.z, pw4.w};
    int curw = pwl[0];
    float ap = 0.f, ag = 0.f;
    #pragma unroll
    for (int j = 0; j < 4; ++j) {
      if (pwl[j] != curw) {
        atomicAdd(&wp[curw], ap);
        atomicAdd(&wg[curw], ag);
        curw = pwl[j]; ap = 0.f; ag = 0.f;
      }
      ap += fmaxf(dpx[j], 0.f);
      ag += dgl[j];
    }
    atomicAdd(&wp[curw], ap);
    atomicAdd(&wg[curw], ag);
  }

  __syncthreads();

  // word-duration loss over words 1..Wn-1 (segment 0 dropped)
  float wd_s = 0.f;
  #pragma unroll
  for (int w = threadIdx.x; w < Wn; w += TPB) {
    if (w != 0) {
      float d = __logf(wp[w] + 1.f) - __logf(wg[w] + 1.f);
      wd_s += d * d;
    }
  }

  pdur_s  = wave_reduce(pdur_s);
  rules_s = wave_reduce(rules_s);
  sp      = wave_reduce(sp);
  sg      = wave_reduce(sg);
  wd_s    = wave_reduce(wd_s);
  if ((threadIdx.x & 63) == 0) {
    atomicAdd(&sacc[0], pdur_s);
    atomicAdd(&sacc[1], rules_s);
    atomicAdd(&sacc[2], sp);
    atomicAdd(&sacc[3], sg);
    atomicAdd(&sacc[4], wd_s);
  }
  __syncthreads();

  if (threadIdx.x == 0) {
    float ds = __logf(sacc[2] + 1.f) - __logf(sacc[3] + 1.f);
    double total = 0.6 * (double)sacc[0] / ((double)Bn * (double)Tn)
                 + 0.3 * (double)sacc[1] / ((double)Bn * (double)Tn)
                 + 0.3 * (double)sacc[4] / ((double)Bn * (double)(Wn - 1))
                 + 0.1 * (double)(ds * ds) / (double)Bn;
    atomicAdd(acc, total);
  }
}

__global__ void finalize_kernel(const double* __restrict__ acc, float* __restrict__ out) {
  out[0] = (float)(*acc);
}

extern "C" void kernel_launch(void* const* d_in, const int* in_sizes, int n_in,
                              void* d_out, int out_size, void* d_ws, size_t ws_size,
                              hipStream_t stream) {
  const float* dur_pred = (const float*)d_in[0];
  const float* dur_gt   = (const float*)d_in[1];
  const int*   ph2word  = (const int*)d_in[2];
  const int*   txt      = (const int*)d_in[3];
  double* acc = (double*)d_ws;

  hipMemsetAsync(d_ws, 0, sizeof(double), stream);
  loss_kernel<<<Bn, TPB, 0, stream>>>(dur_pred, dur_gt, ph2word, txt, acc);
  finalize_kernel<<<1, 1, 0, stream>>>(acc, (float*)d_out);
}

// Round 2
// 202.287 us; speedup vs baseline: 1.0168x; 1.0168x over previous
//
#include <hip/hip_runtime.h>

constexpr int Bn  = 1024;
constexpr int Tn  = 8192;
constexpr int Wn  = 2048;   // NUM_WORDS
constexpr int TPB = 512;
constexpr int NCHUNK = 4;
constexpr int CHUNK  = Tn / NCHUNK;   // 2048 = TPB*4

// Per-position rule evaluation (matches the vectorized reference exactly):
//   INIT_TOKENS  = {94,122,100,92,43,27} -> INIT_DURS {2,3,2,2,5,5}
//   RATIO_TOKENS = {44,28,29,27,121,43}
__device__ __forceinline__ void rule_eval(float dp, float dpn, int tok, bool valid_next,
                                          float& g1, float& g2, float& sa) {
  float expected;
  bool in_init = true;
  switch (tok) {
    case 94:  expected = 2.f; break;
    case 122: expected = 3.f; break;
    case 100: expected = 2.f; break;
    case 92:  expected = 2.f; break;
    case 43:  expected = 5.f; break;
    case 27:  expected = 5.f; break;
    default:  expected = 0.f; in_init = false; break;
  }
  float t1 = dp - expected;
  bool fire1 = in_init && (t1 > 0.f);
  g1 = fire1 ? t1 : 0.f;
  bool in_ratio = (tok == 44) | (tok == 28) | (tok == 29) |
                  (tok == 27) | (tok == 121) | (tok == 43);
  bool fire2 = in_ratio && valid_next && (3.f * dp > dpn);
  g2 = fire2 ? (dp - dpn * (1.f / 3.f)) : 0.f;
  sa = fire2 ? g2 : (fire1 ? g1 : 0.f);
}

__device__ __forceinline__ float wave_reduce(float v) {
  #pragma unroll
  for (int o = 32; o > 0; o >>= 1) v += __shfl_down(v, o, 64);
  return v;
}

// launch_bounds(512,4): 4 waves/EU min -> VGPR cap 128, room for the load pipeline.
__global__ __launch_bounds__(TPB, 4) void loss_kernel(
    const float* __restrict__ dur_pred, const float* __restrict__ dur_gt,
    const int* __restrict__ ph2word, const int* __restrict__ txt,
    double* __restrict__ acc, unsigned* __restrict__ bcount,
    float* __restrict__ out)
{
  __shared__ float wp[Wn];
  __shared__ float wg[Wn];
  __shared__ float sacc[5];   // pdur_s, rules_s, sp, sg, wd_s

  const int row = blockIdx.x;
  const size_t roff = (size_t)row * Tn;
  const float* __restrict__ dpr = dur_pred + roff;
  const float* __restrict__ dgr = dur_gt + roff;
  const int*   __restrict__ pwr = ph2word + roff;
  const int*   __restrict__ tkr = txt + roff;

  const int lane = threadIdx.x & 63;
  const bool is63 = (lane == 63);
  const int tid4 = threadIdx.x * 4;

  // ---- boundary preload (lane 63 only, exec-masked, issued before everything) ----
  // Covers the cross-wave neighbor for j=3 of each chunk: dp[base+4], dp[base+5],
  // tk[base+4]. Off the per-chunk critical path.
  float bdpn[NCHUNK], bggn[NCHUNK];
  #pragma unroll
  for (int c = 0; c < NCHUNK; ++c) { bdpn[c] = 0.f; bggn[c] = 0.f; }
  float ba[NCHUNK], bb[NCHUNK]; int bt[NCHUNK];
  if (is63) {
    #pragma unroll
    for (int c = 0; c < NCHUNK; ++c) {
      const int nb = c * CHUNK + tid4 + 4;
      if (nb < Tn) {
        ba[c] = dpr[nb];
        bb[c] = (nb + 1 < Tn) ? dpr[nb + 1] : 0.f;
        bt[c] = tkr[nb];
      } else { ba[c] = 0.f; bb[c] = 0.f; bt[c] = -1; }
    }
  }

  // ---- prologue: issue chunk 0 main loads ----
  float4 dp_c = *reinterpret_cast<const float4*>(dpr + tid4);
  float4 dg_c = *reinterpret_cast<const float4*>(dgr + tid4);
  int4   pw_c = *reinterpret_cast<const int4*>(pwr + tid4);
  int4   tk_c = *reinterpret_cast<const int4*>(tkr + tid4);

  // finish boundary rule-evals (waits only on the early boundary loads)
  if (is63) {
    #pragma unroll
    for (int c = 0; c < NCHUNK; ++c) {
      const int nb = c * CHUNK + tid4 + 4;
      if (nb < Tn) {
        float ng1, ng2, nsa;
        rule_eval(ba[c], bb[c], bt[c], nb < Tn - 1, ng1, ng2, nsa);
        bdpn[c] = ba[c]; bggn[c] = ng1 + ng2;
      }
    }
  }

  // zero LDS word accumulators (Wn/4 == TPB: one float4 per thread per array)
  {
    const float4 z = {0.f, 0.f, 0.f, 0.f};
    *reinterpret_cast<float4*>(&wp[tid4]) = z;
    *reinterpret_cast<float4*>(&wg[tid4]) = z;
  }
  if (threadIdx.x < 5) sacc[threadIdx.x] = 0.f;
  __syncthreads();

  float pdur_s = 0.f, rules_s = 0.f, sp = 0.f, sg = 0.f;

  #pragma unroll
  for (int c = 0; c < NCHUNK; ++c) {
    const int base = c * CHUNK + tid4;

    // ---- software pipeline: issue chunk c+1 loads before processing chunk c ----
    float4 dp_n, dg_n; int4 pw_n, tk_n;
    if (c + 1 < NCHUNK) {
      const int nb = (c + 1) * CHUNK + tid4;
      dp_n = *reinterpret_cast<const float4*>(dpr + nb);
      dg_n = *reinterpret_cast<const float4*>(dgr + nb);
      pw_n = *reinterpret_cast<const int4*>(pwr + nb);
      tk_n = *reinterpret_cast<const int4*>(tkr + nb);
    }

    // rule evals for j=0..2 (neighbor dp is in-register)
    float g1v[4], g2v[4], sav[4];
    rule_eval(dp_c.x, dp_c.y, tk_c.x, true, g1v[0], g2v[0], sav[0]);
    rule_eval(dp_c.y, dp_c.z, tk_c.y, true, g1v[1], g2v[1], sav[1]);
    rule_eval(dp_c.z, dp_c.w, tk_c.z, true, g1v[2], g2v[2], sav[2]);
    float gg0 = g1v[0] + g2v[0];

    // neighbor for j=3: thread t+1's {dp4.x, gg0} via shuffle; lane63 uses preload
    float dpn3 = __shfl_down(dp_c.x, 1, 64);
    float ggn  = __shfl_down(gg0,   1, 64);
    dpn3 = is63 ? bdpn[c] : dpn3;
    ggn  = is63 ? bggn[c] : ggn;
    rule_eval(dp_c.w, dpn3, tk_c.w, base + 3 < Tn - 1, g1v[3], g2v[3], sav[3]);

    float dpx[4] = {dp_c.x, dp_c.y, dp_c.z, dp_c.w};
    float dgl[4] = {dg_c.x, dg_c.y, dg_c.z, dg_c.w};
    float addv[4] = {g1v[1] + g2v[1], g1v[2] + g2v[2], g1v[3] + g2v[3], ggn};

    #pragma unroll
    for (int j = 0; j < 4; ++j) {
      float dp = dpx[j];
      float dr = dp - sav[j] + addv[j];        // dur_rules[i]
      float lp = __logf(dp + 1.f);
      float dlr = lp - __logf(dr + 1.f);
      rules_s += dlr * dlr;
      float dlg = lp - __logf(dgl[j] + 1.f);
      pdur_s += dlg * dlg;
      sp += fmaxf(dp, 0.f);
      sg += dgl[j];
    }

    // word segment sums: ph2word sorted per row -> run-compress, LDS atomics
    int pwl[4] = {pw_c.x, pw_c.y, pw_c.z, pw_c.w};
    int curw = pwl[0];
    float ap = 0.f, ag = 0.f;
    #pragma unroll
    for (int j = 0; j < 4; ++j) {
      if (pwl[j] != curw) {
        atomicAdd(&wp[curw], ap);
        atomicAdd(&wg[curw], ag);
        curw = pwl[j]; ap = 0.f; ag = 0.f;
      }
      ap += fmaxf(dpx[j], 0.f);
      ag += dgl[j];
    }
    atomicAdd(&wp[curw], ap);
    atomicAdd(&wg[curw], ag);

    // rotate pipeline registers
    if (c + 1 < NCHUNK) { dp_c = dp_n; dg_c = dg_n; pw_c = pw_n; tk_c = tk_n; }
  }

  __syncthreads();

  // word-duration loss over words 1..Wn-1 (segment 0 dropped)
  float wd_s = 0.f;
  #pragma unroll
  for (int w = threadIdx.x; w < Wn; w += TPB) {
    if (w != 0) {
      float d = __logf(wp[w] + 1.f) - __logf(wg[w] + 1.f);
      wd_s += d * d;
    }
  }

  pdur_s  = wave_reduce(pdur_s);
  rules_s = wave_reduce(rules_s);
  sp      = wave_reduce(sp);
  sg      = wave_reduce(sg);
  wd_s    = wave_reduce(wd_s);
  if ((threadIdx.x & 63) == 0) {
    atomicAdd(&sacc[0], pdur_s);
    atomicAdd(&sacc[1], rules_s);
    atomicAdd(&sacc[2], sp);
    atomicAdd(&sacc[3], sg);
    atomicAdd(&sacc[4], wd_s);
  }
  __syncthreads();

  if (threadIdx.x == 0) {
    float ds = __logf(sacc[2] + 1.f) - __logf(sacc[3] + 1.f);
    double total = 0.6 * (double)sacc[0] / ((double)Bn * (double)Tn)
                 + 0.3 * (double)sacc[1] / ((double)Bn * (double)Tn)
                 + 0.3 * (double)sacc[4] / ((double)Bn * (double)(Wn - 1))
                 + 0.1 * (double)(ds * ds) / (double)Bn;
    atomicAdd(acc, total);
    __threadfence();
    unsigned prev = atomicAdd(bcount, 1u);
    if (prev == (unsigned)(Bn - 1)) {
      __threadfence();
      out[0] = (float)(*(volatile double*)acc);
    }
  }
}

extern "C" void kernel_launch(void* const* d_in, const int* in_sizes, int n_in,
                              void* d_out, int out_size, void* d_ws, size_t ws_size,
                              hipStream_t stream) {
  const float* dur_pred = (const float*)d_in[0];
  const float* dur_gt   = (const float*)d_in[1];
  const int*   ph2word  = (const int*)d_in[2];
  const int*   txt      = (const int*)d_in[3];
  double* acc = (double*)d_ws;
  unsigned* bcount = (unsigned*)((char*)d_ws + sizeof(double));

  hipMemsetAsync(d_ws, 0, sizeof(double) + sizeof(unsigned), stream);
  loss_kernel<<<Bn, TPB, 0, stream>>>(dur_pred, dur_gt, ph2word, txt, acc, bcount,
                                      (float*)d_out);
}